// Round 5
// baseline (234.351 us; speedup 1.0000x reference)
//
#include <hip/hip_runtime.h>
#include <math.h>

#define B_DIM 8
#define T_DIM 512
#define H_DIM 768
#define NTOK 511       // T - 1; grid.x == NTOK exactly (no clamp logic)
#define NLAY 9         // 13 - LAYER_START
#define LAYER_START 4
#define NBAND 35       // pairs with |i-j| <= 4 (all that's needed)

// Native clang vector: __builtin_nontemporal_load requires scalar/native
// vector types (HIP_vector_type float4 is rejected — R4 compile error).
typedef float vf4 __attribute__((ext_vector_type(4)));

// Per-token partial outputs and per-token var values. Module globals so we
// never depend on d_ws. Every element is overwritten by wk_a before wk_r
// reads it, so 0xAA poisoning / stale state across calls is irrelevant.
__device__ float g_part[B_DIM * NTOK * H_DIM];  // 12.6 MB
__device__ float g_varp[B_DIM * NTOK];

// banded Gram index: pair (lo, lo+d), d<=4 -> off(d)+lo, off(d)=9d-d(d-1)/2
#define BOFF(d) ((d)*9 - (d) * ((d)-1) / 2)

// DPP move: returns the dpp-selected lane's value (0 for invalid lanes).
// VALU-pipe cross-lane — no DS pipe, no lgkmcnt round trip.
template <int CTRL>
__device__ __forceinline__ float dpp_mov(float x) {
  return __builtin_bit_cast(
      float, __builtin_amdgcn_update_dpp(0, __builtin_bit_cast(int, x), CTRL,
                                         0xF, 0xF, true));
}

// Full-wave (64-lane) sum via gfx9 DPP ladder; total lands in lane 63.
__device__ __forceinline__ float wave_sum_dpp(float x) {
  x += dpp_mov<0x111>(x);  // row_shr:1
  x += dpp_mov<0x112>(x);  // row_shr:2
  x += dpp_mov<0x114>(x);  // row_shr:4
  x += dpp_mov<0x118>(x);  // row_shr:8  -> lane 15 of each row = row sum
  x += dpp_mov<0x142>(x);  // row_bcast:15 -> lane31 = S0+S1, lane63 = S2+S3
  x += dpp_mov<0x143>(x);  // row_bcast:31 -> lane63 = S0+S1+S2+S3
  return x;
}

// ONE TOKEN PER 64-THREAD BLOCK (R5 = R4 retry with native-vector NT loads).
// R2's 4-wave blocks couple wave retirement (all 4 waves hold their slots
// until the final cross-wave sum), so the CU refills load-issuing waves in
// coarse generations. 1-wave blocks retire independently -> continuous HBM
// streaming; lds_out staging and both __syncthreads vanish; grid (511,8)
// needs no inactive-wave clamp. Register footprint per wave unchanged vs R2
// (~175, proven no-spill). R1 lesson: NO min-waves cap — forcing occupancy
// spills v[] wholesale.
__global__ __launch_bounds__(64) void wk_a(const float* __restrict__ ahs) {
  const int t = blockIdx.x;   // 0..510
  const int b = blockIdx.y;   // 0..7
  const int lane = threadIdx.x;

  __shared__ float sG[36];    // banded Gram park (single wave)

  const size_t LSTR = (size_t)B_DIM * T_DIM * H_DIM;  // layer stride (floats)
  const float* lay0 =
      ahs + (size_t)LAYER_START * LSTR + ((size_t)b * T_DIM + t) * H_DIM;

  // ---- load 9 layers x 12 floats (3 x 16B per lane), coalesced.
  //      Nontemporal: pure read-once stream, keep it out of LRU promotion. ----
  vf4 v[NLAY][3];
#pragma unroll
  for (int l = 0; l < NLAY; ++l) {
    const float* base = lay0 + (size_t)l * LSTR;
#pragma unroll
    for (int s = 0; s < 3; ++s) {
      v[l][s] = __builtin_nontemporal_load(
          reinterpret_cast<const vf4*>(base + s * 256 + lane * 4));
    }
  }

  // ---- banded 9x9 Gram: computed AND parked per diagonal d so at most 9
  //      reduction temps are live at once (peak-pressure friendly) ----
#pragma unroll
  for (int d = 0; d <= 4; ++d) {
    float gd[NLAY];
#pragma unroll
    for (int i = 0; i + d < NLAY; ++i) {
      float s0 = 0.f;
#pragma unroll
      for (int s = 0; s < 3; ++s) {
        const vf4 x = v[i][s], y = v[i + d][s];
        s0 += x.x * y.x + x.y * y.y + x.z * y.z + x.w * y.w;
      }
      gd[i] = s0;
    }
    // DPP wave reduction (VALU pipe only); totals land in lane 63
#pragma unroll
    for (int i = 0; i + d < NLAY; ++i) gd[i] = wave_sum_dpp(gd[i]);
    if (lane == 63) {
#pragma unroll
      for (int i = 0; i + d < NLAY; ++i) sG[BOFF(d) + i] = gd[i];
    }
  }
  // Single wave: DS pipe is in-order per wave and the compiler inserts the
  // lgkmcnt wait for the may-alias sG read; wave_barrier blocks reordering.
  // (R1/R2-verified pattern.)
  __builtin_amdgcn_wave_barrier();

  // ---- per-lane k: window rows + Cholesky (R = upper chol of Gram == QR's R
  //      up to row signs, which provably cancel in align/novelty) ----
  const int k = lane < NLAY ? lane : NLAY - 1;
  const int nl = (k >= 2) ? 2 : 0;
  const int nrr = (NLAY - 1 - k) < 2 ? (NLAY - 1 - k) : 2;
  const int m = nl + nrr + 1;  // 3..5, self row last

  auto rowf = [&](int i) -> int {
    return (i < nl) ? (k - 2 + i) : ((i < nl + nrr) ? (k + 1 + i - nl) : k);
  };
  auto GK = [&](int i, int j) -> float {
    int a = rowf(i), c = rowf(j);
    int lo = a < c ? a : c;
    int d = (a < c ? c : a) - lo;  // 0..4 always (window span <= 4)
    return sG[d * 9 - d * (d - 1) / 2 + lo];
  };

  float R[5][5];
#pragma unroll
  for (int j = 0; j < 5; ++j)
#pragma unroll
    for (int i = 0; i < 5; ++i) R[i][j] = 0.f;

#pragma unroll
  for (int j = 0; j < 5; ++j) {
    if (j < m) {
#pragma unroll
      for (int i = 0; i < 5; ++i) {
        if (i < j) {  // compile-time after unroll
          float s = GK(i, j);
#pragma unroll
          for (int p = 0; p < 4; ++p)
            if (p < i) s -= R[p][i] * R[p][j];
          R[i][j] = s / R[i][i];
        }
      }
      float sjj = GK(j, j);
#pragma unroll
      for (int p = 0; p < 4; ++p)
        if (p < j) sjj -= R[p][j] * R[p][j];
      R[j][j] = sqrtf(fmaxf(sjj, 0.f));
    }
  }

  // r = R[:, m-1]
  float r[5];
#pragma unroll
  for (int i = 0; i < 5; ++i)
    r[i] = (m == 3) ? R[i][2] : ((m == 4) ? R[i][3] : R[i][4]);

  // column-normalize Rsub = R[:m-1,:m-1], row means
  float rowmean[4] = {0.f, 0.f, 0.f, 0.f};
#pragma unroll
  for (int j = 0; j < 4; ++j) {
    if (j < m - 1) {
      float cn = 0.f;
#pragma unroll
      for (int i = 0; i < 4; ++i)
        if (i <= j) cn += R[i][j] * R[i][j];
      cn = fmaxf(sqrtf(cn), 1e-12f);
      float inv = 1.f / cn;
#pragma unroll
      for (int i = 0; i < 4; ++i)
        if (i < m - 1) rowmean[i] += R[i][j] * inv;
    }
  }

  const float inv_m1 = 1.f / (float)(m - 1);
  float dotv = 0.f, nrm2 = 0.f;
#pragma unroll
  for (int i = 0; i < 4; ++i) {
    if (i < m - 1) {
      dotv += (rowmean[i] * inv_m1) * r[i];
      nrm2 += r[i] * r[i];
    }
  }
  float align_raw = dotv / sqrtf(nrm2);
  float align_v = 1.f / (align_raw * (float)m * 2.f);
  float rlast = (m == 3) ? r[2] : ((m == 4) ? r[3] : r[4]);
  float nov_v = fabsf(rlast) / sqrtf(nrm2 + rlast * rlast);

  // ---- alphas from lanes 0..8: two-pass shfl, low register count ----
  float asum = 0.f, nsum = 0.f;
#pragma unroll
  for (int l = 0; l < NLAY; ++l) {
    asum += __shfl(align_v, l, 64);
    nsum += __shfl(nov_v, l, 64);
  }
  float c[NLAY];
  float csum = 0.f;
#pragma unroll
  for (int l = 0; l < NLAY; ++l) {
    float a = __shfl(align_v, l, 64) / asum + __shfl(nov_v, l, 64) / nsum;
    c[l] = a;
    csum += a;
  }

  // ---- adjacent-layer cosine sims -> sample variance (ddof=1) ----
  float sims[NLAY - 1];
  float smean = 0.f;
#pragma unroll
  for (int j = 0; j < NLAY - 1; ++j) {
    float num = sG[BOFF(1) + j];
    float den = fmaxf(sqrtf(sG[j]) * sqrtf(sG[j + 1]), 1e-8f);
    sims[j] = num / den;
    smean += sims[j];
  }
  smean *= (1.f / 8.f);
  float var = 0.f;
#pragma unroll
  for (int j = 0; j < NLAY - 1; ++j) {
    float d = sims[j] - smean;
    var += d * d;
  }
  var *= (1.f / 7.f);

  // ---- weighted layer sum from register-resident v, straight to global ----
  const float scale = var / csum;
#pragma unroll
  for (int l = 0; l < NLAY; ++l) c[l] *= scale;

  float* dst = g_part + ((size_t)(b * NTOK + t)) * H_DIM;
#pragma unroll
  for (int s = 0; s < 3; ++s) {
    vf4 o = {0.f, 0.f, 0.f, 0.f};
#pragma unroll
    for (int l = 0; l < NLAY; ++l) {
      o.x += c[l] * v[l][s].x;
      o.y += c[l] * v[l][s].y;
      o.z += c[l] * v[l][s].z;
      o.w += c[l] * v[l][s].w;
    }
    *reinterpret_cast<vf4*>(dst + s * 256 + lane * 4) = o;
  }
  if (lane == 0) g_varp[b * NTOK + t] = var;
}

// grid = (3, B_DIM) x 1024 threads. 4 token-groups x 256 h-threads: group g
// sums tokens j = g, g+4, g+8, ... (<=128 loads/thread, 16-deep MLP), then an
// LDS combine. ssum over the 511 per-token vars via DPP + LDS (threads 0..510
// load one each). Keeps wk_r ~2 µs despite 12.6 MB of partials.
__global__ __launch_bounds__(1024) void wk_r(float* __restrict__ out) {
  const int b = blockIdx.y;
  const int grp = threadIdx.x >> 8;        // 0..3
  const int tid = threadIdx.x & 255;       // 0..255
  const int h = blockIdx.x * 256 + tid;

  __shared__ float s_ws[16];
  __shared__ float s_acc[4][256];

  float vs = (threadIdx.x < NTOK) ? g_varp[b * NTOK + threadIdx.x] : 0.f;
  vs = wave_sum_dpp(vs);  // lane 63 of each of the 16 waves
  if ((threadIdx.x & 63) == 63) s_ws[threadIdx.x >> 6] = vs;

  float acc = 0.f;
#pragma unroll 16
  for (int j = grp; j < NTOK; j += 4)
    acc += g_part[((size_t)(b * NTOK + j)) * H_DIM + h];
  s_acc[grp][tid] = acc;
  __syncthreads();

  if (grp == 0) {
    float ssum = 0.f;
#pragma unroll
    for (int w = 0; w < 16; ++w) ssum += s_ws[w];
    float tot = s_acc[0][tid] + s_acc[1][tid] + s_acc[2][tid] + s_acc[3][tid];
    out[b * H_DIM + h] = tot / ssum;
  }
}

extern "C" void kernel_launch(void* const* d_in, const int* in_sizes, int n_in,
                              void* d_out, int out_size, void* d_ws, size_t ws_size,
                              hipStream_t stream) {
  const float* ahs = (const float*)d_in[0];
  // d_in[1] = attention_mask: unused by the reference computation
  float* out = (float*)d_out;
  (void)d_ws; (void)ws_size;

  wk_a<<<dim3(NTOK, B_DIM), dim3(64), 0, stream>>>(ahs);
  wk_r<<<dim3(3, B_DIM), dim3(1024), 0, stream>>>(out);
}